// Round 5
// baseline (391.970 us; speedup 1.0000x reference)
//
#include <hip/hip_runtime.h>

// (N,C,H,W) = (4,64,96,96), K=3, dilations {1,3,5}. Full-MFMA fp16.
typedef _Float16 f16;
typedef _Float16 f16x8 __attribute__((ext_vector_type(8)));
typedef _Float16 f16x4 __attribute__((ext_vector_type(4)));
typedef float f32x4 __attribute__((ext_vector_type(4)));

#define H 96
#define W 96
#define HWv (H * W)
#define PREC 9604              // padded records per image (98*98)
// ws layout: catp (f16 NHWC, padded 98x98, 512B/record) | gwp | fwp
#define GWP_OFF  19668992      // = 4*9604*512
#define FWP_OFF  19890176      // = GWP_OFF + 216*1024

__device__ __forceinline__ size_t prec_rec(int n, int h, int w) {
    return (size_t)n * PREC + (size_t)(h + 1) * 98 + (w + 1);
}

// ---------------------------------------------------------------------------
// K0: pack gen_w -> gwp A-frags (f16), fuse_w -> fwp A-frags (f16),
//     zero catp padded borders. A-frag: lane&15 = M row, k = (lane>>4)*8+j.
// ---------------------------------------------------------------------------
__global__ __launch_bounds__(256) void prep_kernel(
    const float* __restrict__ gen_w, const float* __restrict__ fuse_w,
    unsigned char* __restrict__ ws)
{
    const int bid = blockIdx.x, tid = threadIdx.x;
    if (bid < 128) {
        const int gid = bid * 256 + tid;
        const int lane = gid & 63;
        if (gid < 18432) {                      // fwp: frag (cot,tap,s)
            const int rest = gid >> 6;          // 0..287 = (cot*9+tap)*8+s
            const int s = rest & 7;
            const int rest2 = rest >> 3;        // cot*9+tap
            const int tap = rest2 % 9, cot = rest2 / 9;
            const int co = cot * 16 + (lane & 15);
            const int ci0 = s * 32 + (lane >> 4) * 8;
            f16x8 v;
#pragma unroll
            for (int j = 0; j < 8; ++j)
                v[j] = (f16)fuse_w[(co * 256 + ci0 + j) * 9 + tap];
            reinterpret_cast<f16x8*>(ws + FWP_OFF)[rest * 64 + lane] = v;
        } else if (gid < 32256) {               // gwp: frag (T,s)
            const int fid = gid - 18432;
            const int lane2 = fid & 63;
            const int rest = fid >> 6;          // 0..215 = T*2+s
            const int T = rest >> 1, s = rest & 1;
            const int o = T * 16 + (lane2 & 15);
            const int cc0 = s * 32 + (lane2 >> 4) * 8;
            f16x8 v;
#pragma unroll
            for (int j = 0; j < 8; ++j)
                v[j] = (f16)gen_w[o * 64 + cc0 + j];
            reinterpret_cast<f16x8*>(ws + GWP_OFF)[rest * 64 + lane2] = v;
        }
    } else {
        // zero padded borders: 4 images * 388 border records * 32 chunks
        const int idx0 = (bid - 128) * 256 + tid;
        for (int k = idx0; k < 49664; k += 32768) {
            const int rec = k >> 5, chunk = k & 31;
            const int n = rec / 388, rr = rec % 388;
            int r, c;
            if (rr < 196) { r = (rr < 98) ? 0 : 97; c = rr % 98; }
            else { const int k2 = rr - 196; c = (k2 < 96) ? 0 : 97; r = 1 + (k2 % 96); }
            const int4 z{0, 0, 0, 0};
            *reinterpret_cast<int4*>(
                ws + ((size_t)n * PREC + (size_t)r * 98 + c) * 512 + chunk * 16) = z;
        }
    }
}

// ---------------------------------------------------------------------------
// K1: kernel-generation GEMM (MFMA f16) + dynamic depthwise conv epilogue.
// Grid 1152 = (n,tile) x gh, 256 thr / 4 waves. px-tile 4x16 (4 N-blocks).
// gh picks groups [gh*6, gh*6+6). MFMA phase: 36 (T_loc,pb) units, 9/wave
// (balanced). klds2 f16 [144][76] (31.4KB total LDS -> 5 blocks/CU; grid
// fully co-resident). B (y) frags in regs. gh==0 also writes x passthrough.
// ---------------------------------------------------------------------------
__global__ __launch_bounds__(256, 4) void gen_dyn_kernel(
    const float* __restrict__ x, const float* __restrict__ y,
    const float* __restrict__ gen_b, unsigned char* __restrict__ ws)
{
    // [0,8192) yls | [8192,30080) klds2 [144][76] f16 | [30080,32128) cslice
    __shared__ __align__(16) unsigned char smem[32128];
    const int tid = threadIdx.x, lane = tid & 63, wv = tid >> 6;
    const int q = lane >> 4;
    const int bid = blockIdx.x;
    const int gh = bid & 1;
    const int bid2 = bid >> 1;
    const int n = bid2 / 144, tile = bid2 % 144;
    const int h0 = (tile / 6) * 4, w0 = (tile % 6) * 16;

    // ---- phase A: x tile -> catp ci[0,64) via swizzled LDS transpose ----
    if (gh == 0) {
        unsigned char* xls = smem + 8192;
#pragma unroll
        for (int it = 0; it < 16; ++it) {
            const int e = tid + it * 256;
            const int cc = e >> 6, p = e & 63;
            const float v = x[(size_t)(n * 64 + cc) * HWv + (h0 + (p >> 4)) * W + w0 + (p & 15)];
            *reinterpret_cast<f16*>(xls + ((p * 128 + cc * 2) ^ ((p & 7) << 4))) = (f16)v;
        }
        __syncthreads();
#pragma unroll
        for (int it = 0; it < 2; ++it) {
            const int px = it * 32 + (tid >> 3), c8 = tid & 7;
            const int4 v = *reinterpret_cast<const int4*>(
                xls + px * 128 + ((c8 ^ (px & 7)) << 4));
            const size_t rec = prec_rec(n, h0 + (px >> 4), w0 + (px & 15));
            *reinterpret_cast<int4*>(ws + rec * 512 + c8 * 16) = v;
        }
        __syncthreads();
    }
    // ---- phase B: y tile -> yls (f16 [px][cc], XOR-swizzled) ----
#pragma unroll
    for (int it = 0; it < 16; ++it) {
        const int e = tid + it * 256;
        const int cc = e >> 6, p = e & 63;
        const float v = y[(size_t)(n * 64 + cc) * HWv + (h0 + (p >> 4)) * W + w0 + (p & 15)];
        *reinterpret_cast<f16*>(smem + ((p * 128 + cc * 2) ^ ((p & 7) << 4))) = (f16)v;
    }
    __syncthreads();

    // ---- B fragments (y) -> registers, kept whole kernel ----
    f16x8 Bf[4][2];
#pragma unroll
    for (int pb = 0; pb < 4; ++pb)
#pragma unroll
        for (int s = 0; s < 2; ++s) {
            const int px = pb * 16 + (lane & 15);
            Bf[pb][s] = *reinterpret_cast<const f16x8*>(
                smem + ((px * 128 + s * 64 + q * 16) ^ ((px & 7) << 4)));
        }

    const f16x8* gwp = reinterpret_cast<const f16x8*>(ws + GWP_OFF);
    f16* klds2 = reinterpret_cast<f16*>(smem + 8192);   // [144][76] f16
    const bool interior = (h0 >= 8) && (h0 <= 84) && (w0 >= 16) && (w0 <= 64);

    for (int gg = 0; gg < 6; ++gg) {
        const int g = gh * 6 + gg;
        // MFMA phase: 9 balanced (T_loc,pb) units per wave
#pragma unroll
        for (int k = 0; k < 9; ++k) {
            const int u = wv * 9 + k;
            const int T_loc = u >> 2, pb = u & 3;
            const int T = g * 9 + T_loc;
            const f16x8 A0 = gwp[(T * 2 + 0) * 64 + lane];
            const f16x8 A1 = gwp[(T * 2 + 1) * 64 + lane];
            const f32x4 gb4 = *reinterpret_cast<const f32x4*>(gen_b + T * 16 + q * 4);
            f32x4 a = {0.f, 0.f, 0.f, 0.f};
            a = __builtin_amdgcn_mfma_f32_16x16x32_f16(A0, Bf[pb][0], a, 0, 0, 0);
            a = __builtin_amdgcn_mfma_f32_16x16x32_f16(A1, Bf[pb][1], a, 0, 0, 0);
            const int px = pb * 16 + (lane & 15);
            const int o0 = T_loc * 16 + q * 4;
#pragma unroll
            for (int r = 0; r < 4; ++r)
                klds2[(o0 + r) * 76 + px] = (f16)(a[r] + gb4[r]);
        }
        __syncthreads();
        // epilogue: dynamic conv for ch in [g*16, g*16+16), 4 px per thread
        {
            const int chl = tid >> 4, px4 = tid & 15;
            const int hloc = px4 >> 2, wl4 = (px4 & 3) * 4;
            const int ch = g * 16 + chl;
            const int bb = ch >> 6, c = ch & 63, d = 2 * bb + 1;
            const int h = h0 + hloc, w = w0 + wl4;
            const float* xc = x + (size_t)(n * 64 + c) * HWv;
            f32x4 racc = {0.f, 0.f, 0.f, 0.f};
            if (interior) {
#pragma unroll
                for (int tap = 0; tap < 9; ++tap) {
                    const f16x4 k4 = *reinterpret_cast<const f16x4*>(
                        &klds2[(chl * 9 + tap) * 76 + hloc * 16 + wl4]);
                    const int hh = h + (tap / 3 - 1) * d;
                    const float* xr = xc + hh * W + (w + (tap % 3 - 1) * d);
                    racc[0] = fmaf((float)k4[0], xr[0], racc[0]);
                    racc[1] = fmaf((float)k4[1], xr[1], racc[1]);
                    racc[2] = fmaf((float)k4[2], xr[2], racc[2]);
                    racc[3] = fmaf((float)k4[3], xr[3], racc[3]);
                }
            } else {
#pragma unroll
                for (int tap = 0; tap < 9; ++tap) {
                    const f16x4 k4 = *reinterpret_cast<const f16x4*>(
                        &klds2[(chl * 9 + tap) * 76 + hloc * 16 + wl4]);
                    const int hh = h + (tap / 3 - 1) * d;
                    if (hh >= 0 && hh < H) {
                        const int wwb = w + (tap % 3 - 1) * d;
#pragma unroll
                        for (int kk = 0; kk < 4; ++kk) {
                            const int wk = wwb + kk;
                            if (wk >= 0 && wk < W)
                                racc[kk] = fmaf((float)k4[kk], xc[hh * W + wk], racc[kk]);
                        }
                    }
                }
            }
            unsigned char* cs = smem + 30080;
#pragma unroll
            for (int kk = 0; kk < 4; ++kk) {
                const int px = hloc * 16 + wl4 + kk;
                *reinterpret_cast<f16*>(
                    cs + ((px * 32 + chl * 2) ^ (((px >> 2) & 3) << 3))) = (f16)racc[kk];
            }
        }
        __syncthreads();
        // flush cslice -> catp ci [64+g*16, 64+g*16+16), coalesced-ish
        {
            const unsigned char* cs = smem + 30080;
            const int px = tid >> 2, chunk = tid & 3;
            const uint2 v = *reinterpret_cast<const uint2*>(
                cs + ((px * 32 + chunk * 8) ^ (((px >> 2) & 3) << 3)));
            const size_t rec = prec_rec(n, h0 + (px >> 4), w0 + (px & 15));
            *reinterpret_cast<uint2*>(ws + rec * 512 + 128 + g * 32 + chunk * 8) = v;
        }
        // next group's klds2 writes guarded by the loop-top pattern:
        // epilogue read of klds2 is before barrier B; writes after loop-top
        // happen post-barrier in the next iteration's unit loop -- but that
        // loop has no barrier before it, so add one:
        __syncthreads();
    }
}

// ---------------------------------------------------------------------------
// K2: fuse conv 3x3 Cin=256 Cout=64 as MFMA implicit GEMM (f16).
// Grid 576 (n,tile), 256 thr / 4 waves. Wave = (pb-pair, co-half): no
// cross-wave reduction, 1 barrier total. B-frags register-cached per s
// (B[4][3] rows x col-shifts -> 96 ds_reads/wave instead of 144).
// ---------------------------------------------------------------------------
__global__ __launch_bounds__(256, 2) void fuse_mfma_kernel(
    const unsigned char* __restrict__ ws, const float* __restrict__ fb,
    float* __restrict__ out)
{
    __shared__ __align__(16) unsigned char smem[55296];  // halo 6x18 recs
    const int tid = threadIdx.x, lane = tid & 63, wv = tid >> 6;
    const int q = lane >> 4;
    const int bid = blockIdx.x;
    const int n = bid / 144, tile = bid % 144;
    const int h0 = (tile / 6) * 4, w0 = (tile % 6) * 16;
    const int pbp = wv & 1, coh = wv >> 1;

    // ---- stage halo (padded rows h0..h0+5, cols w0..w0+17), swizzled ----
    for (int L = tid * 16; L < 55296; L += 4096) {
        const int hpx = L >> 9;
        const int r = hpx / 18, c = hpx - r * 18;
        const int inrec = L & 511;
        const int4 v = *reinterpret_cast<const int4*>(
            ws + ((size_t)n * PREC + (size_t)(h0 + r) * 98 + (w0 + c)) * 512 + inrec);
        *reinterpret_cast<int4*>(smem + (L ^ (((L >> 9) & 7) << 4))) = v;
    }
    __syncthreads();

    f32x4 acc[2][2];
#pragma unroll
    for (int i = 0; i < 2; ++i)
#pragma unroll
        for (int j = 0; j < 2; ++j) acc[i][j] = {0.f, 0.f, 0.f, 0.f};

    const f16x8* fwp = reinterpret_cast<const f16x8*>(ws + FWP_OFF);

    for (int s = 0; s < 8; ++s) {
        // B rows for this wave's pb-pair: rows pbp*2 .. pbp*2+3, 3 col-shifts
        f16x8 B[4][3];
#pragma unroll
        for (int r = 0; r < 4; ++r)
#pragma unroll
            for (int cd = 0; cd < 3; ++cd) {
                const int hpx = (pbp * 2 + r) * 18 + (lane & 15) + cd;
                B[r][cd] = *reinterpret_cast<const f16x8*>(
                    smem + ((hpx * 512 + s * 64 + q * 16) ^ ((hpx & 7) << 4)));
            }
#pragma unroll
        for (int tap = 0; tap < 9; ++tap) {
            const int rb = tap / 3, cd = tap % 3;
            f16x8 Af[2];
#pragma unroll
            for (int j = 0; j < 2; ++j) {
                const int cot = coh * 2 + j;
                Af[j] = fwp[((cot * 9 + tap) * 8 + s) * 64 + lane];
            }
#pragma unroll
            for (int i = 0; i < 2; ++i)
#pragma unroll
                for (int j = 0; j < 2; ++j)
                    acc[i][j] = __builtin_amdgcn_mfma_f32_16x16x32_f16(
                        Af[j], B[i + rb][cd], acc[i][j], 0, 0, 0);
        }
    }

    // ---- bias + store (per-wave, no reduction) ----
#pragma unroll
    for (int i = 0; i < 2; ++i) {
        const int hh = h0 + pbp * 2 + i, ww = w0 + (lane & 15);
#pragma unroll
        for (int j = 0; j < 2; ++j) {
            const int co0 = (coh * 2 + j) * 16 + q * 4;
            const f32x4 fb4 = *reinterpret_cast<const f32x4*>(fb + co0);
#pragma unroll
            for (int r = 0; r < 4; ++r)
                out[(size_t)(n * 64 + co0 + r) * HWv + hh * W + ww]
                    = acc[i][j][r] + fb4[r];
        }
    }
}

// ---------------------------------------------------------------------------
extern "C" void kernel_launch(void* const* d_in, const int* in_sizes, int n_in,
                              void* d_out, int out_size, void* d_ws, size_t ws_size,
                              hipStream_t stream) {
    const float* x      = (const float*)d_in[0];
    const float* y      = (const float*)d_in[1];
    const float* gen_w  = (const float*)d_in[2];
    const float* gen_b  = (const float*)d_in[3];
    const float* fuse_w = (const float*)d_in[4];
    const float* fuse_b = (const float*)d_in[5];
    unsigned char* ws = (unsigned char*)d_ws;

    prep_kernel<<<256, 256, 0, stream>>>(gen_w, fuse_w, ws);
    gen_dyn_kernel<<<1152, 256, 0, stream>>>(x, y, gen_b, ws);
    fuse_mfma_kernel<<<576, 256, 0, stream>>>(ws, fuse_b, (float*)d_out);
}

// Round 6
// 238.398 us; speedup vs baseline: 1.6442x; 1.6442x over previous
//
#include <hip/hip_runtime.h>

// (N,C,H,W) = (4,64,96,96), K=3, dilations {1,3,5}. Full-MFMA fp16.
typedef _Float16 f16;
typedef _Float16 f16x8 __attribute__((ext_vector_type(8)));
typedef _Float16 f16x4 __attribute__((ext_vector_type(4)));
typedef float f32x4 __attribute__((ext_vector_type(4)));

#define H 96
#define W 96
#define HWv (H * W)
#define PREC 9604              // padded records per image (98*98)
// ws layout: catp (f16 NHWC, padded 98x98, 512B/record) | gwp | fwp
#define GWP_OFF  19668992      // = 4*9604*512
#define FWP_OFF  19890176      // = GWP_OFF + 216*1024

__device__ __forceinline__ size_t prec_rec(int n, int h, int w) {
    return (size_t)n * PREC + (size_t)(h + 1) * 98 + (w + 1);
}

// ---------------------------------------------------------------------------
// K0: pack gen_w -> gwp A-frags (f16), fuse_w -> fwp A-frags (f16),
//     zero catp padded borders. A-frag: lane&15 = M row, k = (lane>>4)*8+j.
// ---------------------------------------------------------------------------
__global__ __launch_bounds__(256) void prep_kernel(
    const float* __restrict__ gen_w, const float* __restrict__ fuse_w,
    unsigned char* __restrict__ ws)
{
    const int bid = blockIdx.x, tid = threadIdx.x;
    if (bid < 128) {
        const int gid = bid * 256 + tid;
        const int lane = gid & 63;
        if (gid < 18432) {                      // fwp: frag (cot,tap,s)
            const int rest = gid >> 6;          // 0..287 = (cot*9+tap)*8+s
            const int s = rest & 7;
            const int rest2 = rest >> 3;        // cot*9+tap
            const int tap = rest2 % 9, cot = rest2 / 9;
            const int co = cot * 16 + (lane & 15);
            const int ci0 = s * 32 + (lane >> 4) * 8;
            f16x8 v;
#pragma unroll
            for (int j = 0; j < 8; ++j)
                v[j] = (f16)fuse_w[(co * 256 + ci0 + j) * 9 + tap];
            reinterpret_cast<f16x8*>(ws + FWP_OFF)[rest * 64 + lane] = v;
        } else if (gid < 32256) {               // gwp: frag (T,s)
            const int fid = gid - 18432;
            const int lane2 = fid & 63;
            const int rest = fid >> 6;          // 0..215 = T*2+s
            const int T = rest >> 1, s = rest & 1;
            const int o = T * 16 + (lane2 & 15);
            const int cc0 = s * 32 + (lane2 >> 4) * 8;
            f16x8 v;
#pragma unroll
            for (int j = 0; j < 8; ++j)
                v[j] = (f16)gen_w[o * 64 + cc0 + j];
            reinterpret_cast<f16x8*>(ws + GWP_OFF)[rest * 64 + lane2] = v;
        }
    } else {
        // zero padded borders: 4 images * 388 border records * 32 chunks
        const int idx0 = (bid - 128) * 256 + tid;
        for (int k = idx0; k < 49664; k += 32768) {
            const int rec = k >> 5, chunk = k & 31;
            const int n = rec / 388, rr = rec % 388;
            int r, c;
            if (rr < 196) { r = (rr < 98) ? 0 : 97; c = rr % 98; }
            else { const int k2 = rr - 196; c = (k2 < 96) ? 0 : 97; r = 1 + (k2 % 96); }
            const int4 z{0, 0, 0, 0};
            *reinterpret_cast<int4*>(
                ws + ((size_t)n * PREC + (size_t)r * 98 + c) * 512 + chunk * 16) = z;
        }
    }
}

// ---------------------------------------------------------------------------
// K1: kernel-generation GEMM (MFMA f16) + dynamic depthwise conv epilogue.
// Grid 1152 (n, 2x16-px tile), 256 thr / 4 waves, 29.2 KB LDS -> 5 blk/CU,
// entire grid co-resident (no tail). Block owns its 32 catp records fully.
// 6 group-pairs x 32 ch; waves partition 18 T-tiles {5,5,4,4}, A-frags
// shared across both N-blocks. Flushes are full 64B lines (no RMW).
// ---------------------------------------------------------------------------
__global__ __launch_bounds__(256, 5) void gen_dyn_kernel(
    const float* __restrict__ x, const float* __restrict__ y,
    const float* __restrict__ gen_b, unsigned char* __restrict__ ws)
{
    // [0,4096) yls | [4096,27136) klds2 [288][40] f16 | [27136,29184) cslice
    __shared__ __align__(16) unsigned char smem[29184];
    const int tid = threadIdx.x, lane = tid & 63, wv = tid >> 6;
    const int q = lane >> 4;
    const int bid = blockIdx.x;
    const int n = bid / 288, tile = bid % 288;
    const int h0 = (tile / 6) * 2, w0 = (tile % 6) * 16;

    // ---- phase A: x tile (32px x 64cc) -> catp ci[0,64) via LDS transpose ----
    {
        unsigned char* xls = smem + 4096;
#pragma unroll
        for (int it = 0; it < 8; ++it) {
            const int e = tid + it * 256;
            const int cc = e >> 5, p = e & 31;
            const float v = x[(size_t)(n * 64 + cc) * HWv + (h0 + (p >> 4)) * W + w0 + (p & 15)];
            *reinterpret_cast<f16*>(xls + ((p * 128 + cc * 2) ^ ((p & 7) << 4))) = (f16)v;
        }
        __syncthreads();
        {
            const int px = tid >> 3, c8 = tid & 7;
            const int4 v = *reinterpret_cast<const int4*>(
                xls + px * 128 + ((c8 * 16) ^ ((px & 7) << 4)));
            const size_t rec = prec_rec(n, h0 + (px >> 4), w0 + (px & 15));
            *reinterpret_cast<int4*>(ws + rec * 512 + c8 * 16) = v;
        }
        __syncthreads();
    }
    // ---- phase B: y tile -> yls (f16 [32px][64cc], XOR-swizzled) ----
#pragma unroll
    for (int it = 0; it < 8; ++it) {
        const int e = tid + it * 256;
        const int cc = e >> 5, p = e & 31;
        const float v = y[(size_t)(n * 64 + cc) * HWv + (h0 + (p >> 4)) * W + w0 + (p & 15)];
        *reinterpret_cast<f16*>(smem + ((p * 128 + cc * 2) ^ ((p & 7) << 4))) = (f16)v;
    }
    __syncthreads();

    // ---- B fragments (y) -> registers, kept whole kernel ----
    f16x8 Bf[2][2];
#pragma unroll
    for (int pb = 0; pb < 2; ++pb)
#pragma unroll
        for (int s = 0; s < 2; ++s) {
            const int px = pb * 16 + (lane & 15);
            Bf[pb][s] = *reinterpret_cast<const f16x8*>(
                smem + ((px * 128 + s * 64 + q * 16) ^ ((px & 7) << 4)));
        }

    const f16x8* gwp = reinterpret_cast<const f16x8*>(ws + GWP_OFF);
    f16* klds2 = reinterpret_cast<f16*>(smem + 4096);   // [288][40] f16
    f16* cs = reinterpret_cast<f16*>(smem + 27136);     // [32 px][32 chl] f16
    const bool interior = (h0 >= 6) && (h0 <= 88) && (w0 >= 16) && (w0 <= 64);

    // wave T-partition over 18 T-tiles: {5,5,4,4}
    const int tstart = (wv < 2) ? wv * 5 : 10 + (wv - 2) * 4;
    const int tcnt = (wv < 2) ? 5 : 4;

    for (int gp = 0; gp < 6; ++gp) {
        // MFMA phase: kernels for ch [gp*32, gp*32+32) -> klds2
        for (int ti = 0; ti < tcnt; ++ti) {
            const int T_loc = tstart + ti;
            const int T = gp * 18 + T_loc;
            const f16x8 A0 = gwp[(T * 2 + 0) * 64 + lane];
            const f16x8 A1 = gwp[(T * 2 + 1) * 64 + lane];
            const f32x4 gb4 = *reinterpret_cast<const f32x4*>(gen_b + T * 16 + q * 4);
            const int grp = (T_loc >= 9), t = T_loc - grp * 9;
            const int rowb = grp * 144 + t * 16 + q * 4;
#pragma unroll
            for (int pb = 0; pb < 2; ++pb) {
                f32x4 a = {0.f, 0.f, 0.f, 0.f};
                a = __builtin_amdgcn_mfma_f32_16x16x32_f16(A0, Bf[pb][0], a, 0, 0, 0);
                a = __builtin_amdgcn_mfma_f32_16x16x32_f16(A1, Bf[pb][1], a, 0, 0, 0);
                const int px = pb * 16 + (lane & 15);
#pragma unroll
                for (int r = 0; r < 4; ++r)
                    klds2[(rowb + r) * 40 + px] = (f16)(a[r] + gb4[r]);
            }
        }
        __syncthreads();
        // epilogue: dynamic conv for ch in [gp*32, gp*32+32), 4 px per thread
        {
            const int chl = tid >> 3, px4 = tid & 7;
            const int grp2 = chl >> 4, chl16 = chl & 15;
            const int hloc = px4 >> 2, wl4 = (px4 & 3) * 4;
            const int ch = gp * 32 + chl;
            const int bb = ch >> 6, c = ch & 63, d = 2 * bb + 1;
            const int h = h0 + hloc, w = w0 + wl4;
            const float* xc = x + (size_t)(n * 64 + c) * HWv;
            const int rowb = grp2 * 144 + chl16 * 9;
            f32x4 racc = {0.f, 0.f, 0.f, 0.f};
            if (interior) {
#pragma unroll
                for (int tap = 0; tap < 9; ++tap) {
                    const f16x4 k4 = *reinterpret_cast<const f16x4*>(
                        &klds2[(rowb + tap) * 40 + hloc * 16 + wl4]);
                    const int hh = h + (tap / 3 - 1) * d;
                    const float* xr = xc + hh * W + (w + (tap % 3 - 1) * d);
                    racc[0] = fmaf((float)k4[0], xr[0], racc[0]);
                    racc[1] = fmaf((float)k4[1], xr[1], racc[1]);
                    racc[2] = fmaf((float)k4[2], xr[2], racc[2]);
                    racc[3] = fmaf((float)k4[3], xr[3], racc[3]);
                }
            } else {
#pragma unroll
                for (int tap = 0; tap < 9; ++tap) {
                    const f16x4 k4 = *reinterpret_cast<const f16x4*>(
                        &klds2[(rowb + tap) * 40 + hloc * 16 + wl4]);
                    const int hh = h + (tap / 3 - 1) * d;
                    if (hh >= 0 && hh < H) {
                        const int wwb = w + (tap % 3 - 1) * d;
#pragma unroll
                        for (int kk = 0; kk < 4; ++kk) {
                            const int wk = wwb + kk;
                            if (wk >= 0 && wk < W)
                                racc[kk] = fmaf((float)k4[kk], xc[hh * W + wk], racc[kk]);
                        }
                    }
                }
            }
#pragma unroll
            for (int kk = 0; kk < 4; ++kk) {
                const int px = hloc * 16 + wl4 + kk;
                cs[px * 32 + chl] = (f16)racc[kk];
            }
        }
        __syncthreads();
        // flush cslice -> catp ci [64+gp*32, 96+gp*32): full 64B lines
        {
            const int pxf = tid >> 3, b8 = tid & 7;
            const uint2 v = *reinterpret_cast<const uint2*>(cs + pxf * 32 + b8 * 4);
            const size_t rec = prec_rec(n, h0 + (pxf >> 4), w0 + (pxf & 15));
            *reinterpret_cast<uint2*>(ws + rec * 512 + 128 + gp * 64 + b8 * 8) = v;
        }
        // no barrier needed: next MFMA writes klds2 (epilogue reads done
        // before the last barrier); flush reads cs (disjoint from klds2);
        // next epilogue writes cs only after the next barrier.
    }
}

// ---------------------------------------------------------------------------
// K2: fuse conv 3x3 Cin=256 Cout=64 as MFMA implicit GEMM (f16).
// Grid 576 (n,tile), 256 thr / 4 waves. Wave = (pb-pair, co-half): no
// cross-wave reduction, 1 barrier total. B-frags register-cached per s
// (B[4][3] rows x col-shifts -> 96 ds_reads/wave instead of 144).
// ---------------------------------------------------------------------------
__global__ __launch_bounds__(256, 2) void fuse_mfma_kernel(
    const unsigned char* __restrict__ ws, const float* __restrict__ fb,
    float* __restrict__ out)
{
    __shared__ __align__(16) unsigned char smem[55296];  // halo 6x18 recs
    const int tid = threadIdx.x, lane = tid & 63, wv = tid >> 6;
    const int q = lane >> 4;
    const int bid = blockIdx.x;
    const int n = bid / 144, tile = bid % 144;
    const int h0 = (tile / 6) * 4, w0 = (tile % 6) * 16;
    const int pbp = wv & 1, coh = wv >> 1;

    // ---- stage halo (padded rows h0..h0+5, cols w0..w0+17), swizzled ----
    for (int L = tid * 16; L < 55296; L += 4096) {
        const int hpx = L >> 9;
        const int r = hpx / 18, c = hpx - r * 18;
        const int inrec = L & 511;
        const int4 v = *reinterpret_cast<const int4*>(
            ws + ((size_t)n * PREC + (size_t)(h0 + r) * 98 + (w0 + c)) * 512 + inrec);
        *reinterpret_cast<int4*>(smem + (L ^ (((L >> 9) & 7) << 4))) = v;
    }
    __syncthreads();

    f32x4 acc[2][2];
#pragma unroll
    for (int i = 0; i < 2; ++i)
#pragma unroll
        for (int j = 0; j < 2; ++j) acc[i][j] = {0.f, 0.f, 0.f, 0.f};

    const f16x8* fwp = reinterpret_cast<const f16x8*>(ws + FWP_OFF);

    for (int s = 0; s < 8; ++s) {
        // B rows for this wave's pb-pair: rows pbp*2 .. pbp*2+3, 3 col-shifts
        f16x8 B[4][3];
#pragma unroll
        for (int r = 0; r < 4; ++r)
#pragma unroll
            for (int cd = 0; cd < 3; ++cd) {
                const int hpx = (pbp * 2 + r) * 18 + (lane & 15) + cd;
                B[r][cd] = *reinterpret_cast<const f16x8*>(
                    smem + ((hpx * 512 + s * 64 + q * 16) ^ ((hpx & 7) << 4)));
            }
#pragma unroll
        for (int tap = 0; tap < 9; ++tap) {
            const int rb = tap / 3, cd = tap % 3;
            f16x8 Af[2];
#pragma unroll
            for (int j = 0; j < 2; ++j) {
                const int cot = coh * 2 + j;
                Af[j] = fwp[((cot * 9 + tap) * 8 + s) * 64 + lane];
            }
#pragma unroll
            for (int i = 0; i < 2; ++i)
#pragma unroll
                for (int j = 0; j < 2; ++j)
                    acc[i][j] = __builtin_amdgcn_mfma_f32_16x16x32_f16(
                        Af[j], B[i + rb][cd], acc[i][j], 0, 0, 0);
        }
    }

    // ---- bias + store (per-wave, no reduction) ----
#pragma unroll
    for (int i = 0; i < 2; ++i) {
        const int hh = h0 + pbp * 2 + i, ww = w0 + (lane & 15);
#pragma unroll
        for (int j = 0; j < 2; ++j) {
            const int co0 = (coh * 2 + j) * 16 + q * 4;
            const f32x4 fb4 = *reinterpret_cast<const f32x4*>(fb + co0);
#pragma unroll
            for (int r = 0; r < 4; ++r)
                out[(size_t)(n * 64 + co0 + r) * HWv + hh * W + ww]
                    = acc[i][j][r] + fb4[r];
        }
    }
}

// ---------------------------------------------------------------------------
extern "C" void kernel_launch(void* const* d_in, const int* in_sizes, int n_in,
                              void* d_out, int out_size, void* d_ws, size_t ws_size,
                              hipStream_t stream) {
    const float* x      = (const float*)d_in[0];
    const float* y      = (const float*)d_in[1];
    const float* gen_w  = (const float*)d_in[2];
    const float* gen_b  = (const float*)d_in[3];
    const float* fuse_w = (const float*)d_in[4];
    const float* fuse_b = (const float*)d_in[5];
    unsigned char* ws = (unsigned char*)d_ws;

    prep_kernel<<<256, 256, 0, stream>>>(gen_w, fuse_w, ws);
    gen_dyn_kernel<<<1152, 256, 0, stream>>>(x, y, gen_b, ws);
    fuse_mfma_kernel<<<576, 256, 0, stream>>>(ws, fuse_b, (float*)d_out);
}

// Round 7
// 202.550 us; speedup vs baseline: 1.9352x; 1.1770x over previous
//
#include <hip/hip_runtime.h>

// (N,C,H,W) = (4,64,96,96), K=3, dilations {1,3,5}. Full-MFMA fp16.
typedef _Float16 f16;
typedef _Float16 f16x8 __attribute__((ext_vector_type(8)));
typedef _Float16 f16x4 __attribute__((ext_vector_type(4)));
typedef float f32x4 __attribute__((ext_vector_type(4)));

#define H 96
#define W 96
#define HWv (H * W)
#define PREC 9604              // padded records per image (98*98)
// ws layout: catp (f16 NHWC, padded 98x98, 512B/record) | gwp | fwp
#define GWP_OFF  19668992      // = 4*9604*512
#define FWP_OFF  19890176      // = GWP_OFF + 216*1024

__device__ __forceinline__ size_t prec_rec(int n, int h, int w) {
    return (size_t)n * PREC + (size_t)(h + 1) * 98 + (w + 1);
}

// ---------------------------------------------------------------------------
// K0: pack gen_w -> gwp A-frags, fuse_w -> fwp A-frags, zero catp borders.
// A-frag: lane&15 = M row, k = (lane>>4)*8+j.   (unchanged from R4-R6)
// ---------------------------------------------------------------------------
__global__ __launch_bounds__(256) void prep_kernel(
    const float* __restrict__ gen_w, const float* __restrict__ fuse_w,
    unsigned char* __restrict__ ws)
{
    const int bid = blockIdx.x, tid = threadIdx.x;
    if (bid < 128) {
        const int gid = bid * 256 + tid;
        const int lane = gid & 63;
        if (gid < 18432) {                      // fwp: frag (cot,tap,s)
            const int rest = gid >> 6;
            const int s = rest & 7;
            const int rest2 = rest >> 3;
            const int tap = rest2 % 9, cot = rest2 / 9;
            const int co = cot * 16 + (lane & 15);
            const int ci0 = s * 32 + (lane >> 4) * 8;
            f16x8 v;
#pragma unroll
            for (int j = 0; j < 8; ++j)
                v[j] = (f16)fuse_w[(co * 256 + ci0 + j) * 9 + tap];
            reinterpret_cast<f16x8*>(ws + FWP_OFF)[rest * 64 + lane] = v;
        } else if (gid < 32256) {               // gwp: frag (T,s)
            const int fid = gid - 18432;
            const int lane2 = fid & 63;
            const int rest = fid >> 6;
            const int T = rest >> 1, s = rest & 1;
            const int o = T * 16 + (lane2 & 15);
            const int cc0 = s * 32 + (lane2 >> 4) * 8;
            f16x8 v;
#pragma unroll
            for (int j = 0; j < 8; ++j)
                v[j] = (f16)gen_w[o * 64 + cc0 + j];
            reinterpret_cast<f16x8*>(ws + GWP_OFF)[rest * 64 + lane2] = v;
        }
    } else {
        const int idx0 = (bid - 128) * 256 + tid;
        for (int k = idx0; k < 49664; k += 32768) {
            const int rec = k >> 5, chunk = k & 31;
            const int n = rec / 388, rr = rec % 388;
            int r, c;
            if (rr < 196) { r = (rr < 98) ? 0 : 97; c = rr % 98; }
            else { const int k2 = rr - 196; c = (k2 < 96) ? 0 : 97; r = 1 + (k2 % 96); }
            const int4 z{0, 0, 0, 0};
            *reinterpret_cast<int4*>(
                ws + ((size_t)n * PREC + (size_t)r * 98 + c) * 512 + chunk * 16) = z;
        }
    }
}

// ---------------------------------------------------------------------------
// K1: gen GEMM (MFMA f16) + dynamic depthwise conv, WAVE-INDEPENDENT.
// Grid 2304 (n, 1x16-px tile), 256 thr / 4 waves, 25.1 KB LDS -> 5 blk/CU.
// 2 barriers total (stage). Then each wave owns 3 chunks of 16 channels
// end-to-end: MFMA(9 T-tiles) -> own klds -> lgkmcnt -> epilogue -> own cs
// -> flush (32B/record). Block fully owns its 16 catp records.
// ---------------------------------------------------------------------------
__global__ __launch_bounds__(256, 5) void gen_dyn_kernel(
    const float* __restrict__ x, const float* __restrict__ y,
    const float* __restrict__ gen_b, unsigned char* __restrict__ ws)
{
    // [0,2048) yls (-> per-wave cs after Bf read) | [2048,25088) klds 4x5760
    // xls (2KB) overlays klds wave0 region during stage phase.
    __shared__ __align__(16) unsigned char smem[25088];
    const int tid = threadIdx.x, lane = tid & 63, wv = tid >> 6;
    const int q4 = lane >> 4, px = lane & 15;
    const int bid = blockIdx.x;
    const int n = bid / 576, rem = bid % 576;
    const int h0 = rem / 6, w0 = (rem % 6) * 16;

    unsigned char* yls = smem;          // [16px][64c] f16, 128B rows, swizzled
    unsigned char* xls = smem + 2048;

    // ---- stage x & y tiles (16px x 64c), f32x4 loads + transpose to LDS ----
    {
        const int scc = tid >> 2, sp4 = (tid & 3) * 4;
        const size_t gb = (size_t)(n * 64 + scc) * HWv + h0 * W + w0 + sp4;
        const f32x4 xv4 = *reinterpret_cast<const f32x4*>(x + gb);
        const f32x4 yv4 = *reinterpret_cast<const f32x4*>(y + gb);
#pragma unroll
        for (int k = 0; k < 4; ++k) {
            const int p = sp4 + k;
            const int off = (p * 128 + scc * 2) ^ ((p & 7) << 4);
            *reinterpret_cast<f16*>(xls + off) = (f16)xv4[k];
            *reinterpret_cast<f16*>(yls + off) = (f16)yv4[k];
        }
    }
    __syncthreads();
    // x passthrough flush (catp bytes [0,128) of this block's 16 records)
    if (tid < 128) {
        const int pxf = tid >> 3, c16 = tid & 7;
        const int4 v = *reinterpret_cast<const int4*>(
            xls + ((pxf * 128 + c16 * 16) ^ ((pxf & 7) << 4)));
        *reinterpret_cast<int4*>(ws + prec_rec(n, h0, w0 + pxf) * 512 + c16 * 16) = v;
    }
    // B fragments (y) -> registers
    f16x8 Bf[2];
#pragma unroll
    for (int s = 0; s < 2; ++s)
        Bf[s] = *reinterpret_cast<const f16x8*>(
            yls + ((px * 128 + s * 64 + q4 * 16) ^ ((px & 7) << 4)));
    __syncthreads();
    // ---- after this point: NO barriers. klds/cs are per-wave. ----

    f16* klds = reinterpret_cast<f16*>(smem + 2048 + wv * 5760); // [144][20] f16
    f16* cs   = reinterpret_cast<f16*>(smem + wv * 512);         // [16px][16ch]
    const f16x8* gwp = reinterpret_cast<const f16x8*>(ws + GWP_OFF);
    const bool interior = (h0 >= 5) && (h0 <= 90) && (w0 >= 16) && (w0 <= 64);
    const int chl = lane >> 2, wu = lane & 3;

    for (int qi = 0; qi < 3; ++qi) {
        const int q = wv * 3 + qi;      // chunk: channels [q*16, q*16+16)
        // --- MFMA: 9 T-tiles (144 kernel rows) -> klds ---
#pragma unroll 3
        for (int t = 0; t < 9; ++t) {
            const int T = q * 9 + t;
            const f16x8 A0 = gwp[(T * 2 + 0) * 64 + lane];
            const f16x8 A1 = gwp[(T * 2 + 1) * 64 + lane];
            const f32x4 gb4 = *reinterpret_cast<const f32x4*>(gen_b + T * 16 + q4 * 4);
            f32x4 a = {0.f, 0.f, 0.f, 0.f};
            a = __builtin_amdgcn_mfma_f32_16x16x32_f16(A0, Bf[0], a, 0, 0, 0);
            a = __builtin_amdgcn_mfma_f32_16x16x32_f16(A1, Bf[1], a, 0, 0, 0);
#pragma unroll
            for (int r = 0; r < 4; ++r)
                klds[(t * 16 + q4 * 4 + r) * 20 + px] = (f16)(a[r] + gb4[r]);
        }
        asm volatile("s_waitcnt lgkmcnt(0)" ::: "memory");
        __builtin_amdgcn_sched_barrier(0);
        // --- dynconv epilogue: lane = (chl, wu): ch q*16+chl, px wu*4..+3 ---
        {
            const int ch = q * 16 + chl;
            const int bb = ch >> 6, c = ch & 63, d = 2 * bb + 1;
            const int wbase = w0 + wu * 4;
            const float* xc = x + (size_t)(n * 64 + c) * HWv;
            f32x4 racc = {0.f, 0.f, 0.f, 0.f};
            if (interior) {
#pragma unroll
                for (int tap = 0; tap < 9; ++tap) {
                    const f16x4 k4 = *reinterpret_cast<const f16x4*>(
                        &klds[(chl * 9 + tap) * 20 + wu * 4]);
                    const int hh = h0 + (tap / 3 - 1) * d;
                    const float* xr = xc + hh * W + wbase + (tap % 3 - 1) * d;
                    racc[0] = fmaf((float)k4[0], xr[0], racc[0]);
                    racc[1] = fmaf((float)k4[1], xr[1], racc[1]);
                    racc[2] = fmaf((float)k4[2], xr[2], racc[2]);
                    racc[3] = fmaf((float)k4[3], xr[3], racc[3]);
                }
            } else {
#pragma unroll
                for (int tap = 0; tap < 9; ++tap) {
                    const f16x4 k4 = *reinterpret_cast<const f16x4*>(
                        &klds[(chl * 9 + tap) * 20 + wu * 4]);
                    const int hh = h0 + (tap / 3 - 1) * d;
                    if (hh >= 0 && hh < H) {
                        const int wwb = wbase + (tap % 3 - 1) * d;
#pragma unroll
                        for (int kk = 0; kk < 4; ++kk) {
                            const int wk = wwb + kk;
                            if (wk >= 0 && wk < W)
                                racc[kk] = fmaf((float)k4[kk], xc[hh * W + wk], racc[kk]);
                        }
                    }
                }
            }
#pragma unroll
            for (int kk = 0; kk < 4; ++kk)
                cs[(wu * 4 + kk) * 16 + chl] = (f16)racc[kk];
        }
        asm volatile("s_waitcnt lgkmcnt(0)" ::: "memory");
        __builtin_amdgcn_sched_barrier(0);
        // --- flush this chunk: 32B per record at offset 128 + q*32 ---
        if (lane < 32) {
            const int pxf = lane >> 1, half = lane & 1;
            const int4 v = *reinterpret_cast<const int4*>(cs + pxf * 16 + half * 8);
            *reinterpret_cast<int4*>(
                ws + prec_rec(n, h0, w0 + pxf) * 512 + 128 + q * 32 + half * 16) = v;
        }
        __builtin_amdgcn_sched_barrier(0);   // keep next MFMA writes after flush reads
    }
}

// ---------------------------------------------------------------------------
// K2: fuse conv 3x3 Cin=256 Cout=64, MFMA implicit GEMM, s-sliced staging.
// Grid 576 (n, 4x16 tile), 256 thr / 4 waves = (pb-pair, co-half).
// Halo staged one 32-ci slice at a time: 2 x 6.75 KB double-buffered LDS,
// slice s+1 prefetched to regs during MFMA(s) (T14). 1 barrier per slice.
// ---------------------------------------------------------------------------
__global__ __launch_bounds__(256, 3) void fuse_mfma_kernel(
    const unsigned char* __restrict__ ws, const float* __restrict__ fb,
    float* __restrict__ out)
{
    __shared__ __align__(16) unsigned char smem[13824];  // 2 x [108 hpx][64B]
    const int tid = threadIdx.x, lane = tid & 63, wv = tid >> 6;
    const int q4 = lane >> 4;
    const int bid = blockIdx.x;
    const int n = bid / 144, tile = bid % 144;
    const int h0 = (tile / 6) * 4, w0 = (tile % 6) * 16;
    const int pbp = wv & 1, coh = wv >> 1;

    // staging assignment: 432 16B-chunks (108 records x 4), <=2 per thread
    const int e0 = tid, e1 = tid + 256;
    const int hpx0 = e0 >> 2, cc0 = e0 & 3;
    const int hpx1 = e1 >> 2, cc1 = e1 & 3;
    const size_t rb0 = prec_rec(n, h0 - 1 + hpx0 / 18, w0 - 1 + hpx0 % 18) * 512;
    const size_t rb1 = prec_rec(n, h0 - 1 + hpx1 / 18, w0 - 1 + hpx1 % 18) * 512;
    const int dso0 = hpx0 * 64 + ((cc0 * 16) ^ (((hpx0 >> 1) & 3) << 4));
    const int dso1 = hpx1 * 64 + ((cc1 * 16) ^ (((hpx1 >> 1) & 3) << 4));

    // stage slice s=0
    *reinterpret_cast<int4*>(smem + dso0) =
        *reinterpret_cast<const int4*>(ws + rb0 + cc0 * 16);
    if (tid < 176)
        *reinterpret_cast<int4*>(smem + dso1) =
            *reinterpret_cast<const int4*>(ws + rb1 + cc1 * 16);
    __syncthreads();

    f32x4 acc[2][2];
#pragma unroll
    for (int i = 0; i < 2; ++i)
#pragma unroll
        for (int j = 0; j < 2; ++j) acc[i][j] = {0.f, 0.f, 0.f, 0.f};

    const f16x8* fwp = reinterpret_cast<const f16x8*>(ws + FWP_OFF);

    for (int s = 0; s < 8; ++s) {
        unsigned char* buf  = smem + (s & 1) * 6912;
        unsigned char* nbuf = smem + ((s & 1) ^ 1) * 6912;
        // prefetch slice s+1 into registers (latency hides under MFMA)
        int4 pf0{0,0,0,0}, pf1{0,0,0,0};
        if (s < 7) {
            pf0 = *reinterpret_cast<const int4*>(ws + rb0 + (s + 1) * 64 + cc0 * 16);
            if (tid < 176)
                pf1 = *reinterpret_cast<const int4*>(ws + rb1 + (s + 1) * 64 + cc1 * 16);
        }
        // B frags: rows pbp*2 .. pbp*2+3, 3 col-shifts (register-cached)
        f16x8 B[4][3];
#pragma unroll
        for (int r = 0; r < 4; ++r)
#pragma unroll
            for (int cd = 0; cd < 3; ++cd) {
                const int hpx = (pbp * 2 + r) * 18 + (lane & 15) + cd;
                B[r][cd] = *reinterpret_cast<const f16x8*>(
                    buf + hpx * 64 + ((q4 * 16) ^ (((hpx >> 1) & 3) << 4)));
            }
#pragma unroll
        for (int tap = 0; tap < 9; ++tap) {
            const int rb = tap / 3, cd = tap % 3;
            f16x8 Af[2];
#pragma unroll
            for (int j = 0; j < 2; ++j)
                Af[j] = fwp[(((coh * 2 + j) * 9 + tap) * 8 + s) * 64 + lane];
#pragma unroll
            for (int i = 0; i < 2; ++i)
#pragma unroll
                for (int j = 0; j < 2; ++j)
                    acc[i][j] = __builtin_amdgcn_mfma_f32_16x16x32_f16(
                        Af[j], B[i + rb][cd], acc[i][j], 0, 0, 0);
        }
        if (s < 7) {
            *reinterpret_cast<int4*>(nbuf + dso0) = pf0;
            if (tid < 176)
                *reinterpret_cast<int4*>(nbuf + dso1) = pf1;
        }
        __syncthreads();
    }

    // ---- bias + store (per-wave, no reduction) ----
#pragma unroll
    for (int i = 0; i < 2; ++i) {
        const int hh = h0 + pbp * 2 + i, ww = w0 + (lane & 15);
#pragma unroll
        for (int j = 0; j < 2; ++j) {
            const int co0 = (coh * 2 + j) * 16 + q4 * 4;
            const f32x4 fb4 = *reinterpret_cast<const f32x4*>(fb + co0);
#pragma unroll
            for (int r = 0; r < 4; ++r)
                out[(size_t)(n * 64 + co0 + r) * HWv + hh * W + ww]
                    = acc[i][j][r] + fb4[r];
        }
    }
}

// ---------------------------------------------------------------------------
extern "C" void kernel_launch(void* const* d_in, const int* in_sizes, int n_in,
                              void* d_out, int out_size, void* d_ws, size_t ws_size,
                              hipStream_t stream) {
    const float* x      = (const float*)d_in[0];
    const float* y      = (const float*)d_in[1];
    const float* gen_w  = (const float*)d_in[2];
    const float* gen_b  = (const float*)d_in[3];
    const float* fuse_w = (const float*)d_in[4];
    const float* fuse_b = (const float*)d_in[5];
    unsigned char* ws = (unsigned char*)d_ws;

    prep_kernel<<<256, 256, 0, stream>>>(gen_w, fuse_w, ws);
    gen_dyn_kernel<<<2304, 256, 0, stream>>>(x, y, gen_b, ws);
    fuse_mfma_kernel<<<576, 256, 0, stream>>>(ws, fuse_b, (float*)d_out);
}